// Round 3
// baseline (14.205 us; speedup 1.0000x reference)
//
#include <hip/hip_runtime.h>

// ChannelSimLoss1D, single-workgroup version (zero device-scope sync).
// Closed form per sample: ||rowNormGram(x)-rowNormGram(y)||_F^2
//   = nnz(x) + nnz(y) - 2 * (sum_i sign(x_i)sign(y_i)) * cos(x,y)
// out = mean_b / C.
// B=32, C=2048, fp32. Total input 512 KB -> one CU, 16 waves, each wave owns
// 2 samples. No atomics/fences/partials: immune to ws initial state, trivially
// deterministic under graph replay.

constexpr int B = 32;
constexpr int C = 2048;
constexpr int THREADS = 1024;   // 16 waves; wave w handles samples 2w, 2w+1

__global__ __launch_bounds__(THREADS) void csl_single(const float* __restrict__ x,
                                                      const float* __restrict__ y,
                                                      float* __restrict__ out) {
    const int tid  = threadIdx.x;
    const int wave = tid >> 6;
    const int lane = tid & 63;
    const int s0 = wave * 2;
    const int s1 = s0 + 1;

    const float4* x40 = reinterpret_cast<const float4*>(x + (size_t)s0 * C);
    const float4* x41 = reinterpret_cast<const float4*>(x + (size_t)s1 * C);
    const float4* y40 = reinterpret_cast<const float4*>(y + (size_t)s0 * C);
    const float4* y41 = reinterpret_cast<const float4*>(y + (size_t)s1 * C);

    // 6 named accumulators per sample (no runtime-indexed arrays -> no scratch)
    float a_sx2 = 0.f, a_sy2 = 0.f, a_sxy = 0.f, a_sp = 0.f, a_cx = 0.f, a_cy = 0.f;
    float b_sx2 = 0.f, b_sy2 = 0.f, b_sxy = 0.f, b_sp = 0.f, b_cx = 0.f, b_cy = 0.f;

    auto accum = [](float u, float v, float& sx2, float& sy2, float& sxy,
                    float& sp, float& cx, float& cy) {
        sx2 = fmaf(u, u, sx2);
        sy2 = fmaf(v, v, sy2);
        sxy = fmaf(u, v, sxy);
        const float su = (u > 0.f) ? 1.f : ((u < 0.f) ? -1.f : 0.f);
        const float sv = (v > 0.f) ? 1.f : ((v < 0.f) ? -1.f : 0.f);
        sp += su * sv;
        cx += (u != 0.f) ? 1.f : 0.f;   // nnz; sign(0)=0 covers the EPS branch
        cy += (v != 0.f) ? 1.f : 0.f;
    };

    #pragma unroll
    for (int j = 0; j < C / 4 / 64; ++j) {        // 8 iterations
        const int idx = lane + 64 * j;            // coalesced per wave
        const float4 xa = x40[idx];
        const float4 ya = y40[idx];
        const float4 xb = x41[idx];
        const float4 yb = y41[idx];
        accum(xa.x, ya.x, a_sx2, a_sy2, a_sxy, a_sp, a_cx, a_cy);
        accum(xa.y, ya.y, a_sx2, a_sy2, a_sxy, a_sp, a_cx, a_cy);
        accum(xa.z, ya.z, a_sx2, a_sy2, a_sxy, a_sp, a_cx, a_cy);
        accum(xa.w, ya.w, a_sx2, a_sy2, a_sxy, a_sp, a_cx, a_cy);
        accum(xb.x, yb.x, b_sx2, b_sy2, b_sxy, b_sp, b_cx, b_cy);
        accum(xb.y, yb.y, b_sx2, b_sy2, b_sxy, b_sp, b_cx, b_cy);
        accum(xb.z, yb.z, b_sx2, b_sy2, b_sxy, b_sp, b_cx, b_cy);
        accum(xb.w, yb.w, b_sx2, b_sy2, b_sxy, b_sp, b_cx, b_cy);
    }

    // wave64 shuffle reduce, 12 fused chains
    #pragma unroll
    for (int off = 32; off >= 1; off >>= 1) {
        a_sx2 += __shfl_down(a_sx2, off);  a_sy2 += __shfl_down(a_sy2, off);
        a_sxy += __shfl_down(a_sxy, off);  a_sp  += __shfl_down(a_sp,  off);
        a_cx  += __shfl_down(a_cx,  off);  a_cy  += __shfl_down(a_cy,  off);
        b_sx2 += __shfl_down(b_sx2, off);  b_sy2 += __shfl_down(b_sy2, off);
        b_sxy += __shfl_down(b_sxy, off);  b_sp  += __shfl_down(b_sp,  off);
        b_cx  += __shfl_down(b_cx,  off);  b_cy  += __shfl_down(b_cy,  off);
    }

    __shared__ float vals[B];
    if (lane == 0) {
        {
            const float denom = fmaxf(sqrtf(a_sx2) * sqrtf(a_sy2), 1e-24f);
            vals[s0] = a_cx + a_cy - 2.f * a_sp * (a_sxy / denom);
        }
        {
            const float denom = fmaxf(sqrtf(b_sx2) * sqrtf(b_sy2), 1e-24f);
            vals[s1] = b_cx + b_cy - 2.f * b_sp * (b_sxy / denom);
        }
    }
    __syncthreads();

    if (tid < 64) {
        float v = (tid < B) ? vals[tid] : 0.f;
        #pragma unroll
        for (int off = 32; off >= 1; off >>= 1) v += __shfl_down(v, off);
        if (tid == 0) out[0] = v * (1.f / (float)(B * C));
    }
}

extern "C" void kernel_launch(void* const* d_in, const int* in_sizes, int n_in,
                              void* d_out, int out_size, void* d_ws, size_t ws_size,
                              hipStream_t stream) {
    const float* x = (const float*)d_in[0];
    const float* y = (const float*)d_in[1];
    csl_single<<<1, THREADS, 0, stream>>>(x, y, (float*)d_out);
}

// Round 4
// 10.168 us; speedup vs baseline: 1.3970x; 1.3970x over previous
//
#include <hip/hip_runtime.h>

// ChannelSimLoss1D, single-dispatch, 8-block version.
// Closed form per sample: ||rowNormGram(x)-rowNormGram(y)||_F^2
//   = nnz(x) + nnz(y) - 2 * (sum_i sign(x_i)sign(y_i)) * cos(x,y)
// out = mean_b / C.  B=32, C=2048, fp32.
// 8 blocks x 1024 threads: block owns 4 samples (wave w -> sample w>>2,
// quarter w&3), publishes ONE partial (sum of its 4 sample values).
// Finish: atomicInc(counter,7) cycles mod 8 -> exactly one block sees old==6
// per call for ANY initial counter value (0xAA poison or steady-state 7),
// deterministic under graph replay with no re-poisoning.

constexpr int B = 32;
constexpr int C = 2048;
constexpr int THREADS = 1024;           // 16 waves
constexpr int SAMPLES_PER_BLOCK = 4;
constexpr int NBLOCKS = B / SAMPLES_PER_BLOCK;   // 8

__global__ __launch_bounds__(THREADS) void csl_fused8(const float* __restrict__ x,
                                                      const float* __restrict__ y,
                                                      float* __restrict__ partials,
                                                      unsigned* __restrict__ counter,
                                                      float* __restrict__ out) {
    const int tid  = threadIdx.x;
    const int wave = tid >> 6;          // 0..15
    const int lane = tid & 63;
    const int s    = blockIdx.x * SAMPLES_PER_BLOCK + (wave >> 2);  // sample
    const int q    = wave & 3;                                       // quarter

    const float4* x4 = reinterpret_cast<const float4*>(x + (size_t)s * C + q * (C / 4));
    const float4* y4 = reinterpret_cast<const float4*>(y + (size_t)s * C + q * (C / 4));

    float sx2 = 0.f, sy2 = 0.f, sxy = 0.f, sp = 0.f, cx = 0.f, cy = 0.f;
    #pragma unroll
    for (int j = 0; j < 2; ++j) {                 // C/4 floats per wave = 2 float4/lane
        const float4 a  = x4[lane + 64 * j];
        const float4 c4 = y4[lane + 64 * j];
        const float av[4] = {a.x, a.y, a.z, a.w};
        const float bv[4] = {c4.x, c4.y, c4.z, c4.w};
        #pragma unroll
        for (int k = 0; k < 4; ++k) {
            const float u = av[k], v = bv[k];
            sx2 = fmaf(u, u, sx2);
            sy2 = fmaf(v, v, sy2);
            sxy = fmaf(u, v, sxy);
            const float su = (u > 0.f) ? 1.f : ((u < 0.f) ? -1.f : 0.f);
            const float sv = (v > 0.f) ? 1.f : ((v < 0.f) ? -1.f : 0.f);
            sp += su * sv;
            cx += (u != 0.f) ? 1.f : 0.f;   // nnz; sign(0)=0 covers EPS branch
            cy += (v != 0.f) ? 1.f : 0.f;
        }
    }

    // 6-chain wave64 shuffle reduce
    #pragma unroll
    for (int off = 32; off >= 1; off >>= 1) {
        sx2 += __shfl_down(sx2, off);
        sy2 += __shfl_down(sy2, off);
        sxy += __shfl_down(sxy, off);
        sp  += __shfl_down(sp,  off);
        cx  += __shfl_down(cx,  off);
        cy  += __shfl_down(cy,  off);
    }

    __shared__ float red[16][6];
    __shared__ float vals[SAMPLES_PER_BLOCK];
    __shared__ bool  amLast;
    if (lane == 0) {
        red[wave][0] = sx2; red[wave][1] = sy2; red[wave][2] = sxy;
        red[wave][3] = sp;  red[wave][4] = cx;  red[wave][5] = cy;
    }
    __syncthreads();

    if (tid < SAMPLES_PER_BLOCK) {                // thread i combines sample i
        const int w0 = tid * 4;
        float t0 = 0.f, t1 = 0.f, t2 = 0.f, t3 = 0.f, t4 = 0.f, t5 = 0.f;
        #pragma unroll
        for (int w = 0; w < 4; ++w) {
            t0 += red[w0 + w][0]; t1 += red[w0 + w][1]; t2 += red[w0 + w][2];
            t3 += red[w0 + w][3]; t4 += red[w0 + w][4]; t5 += red[w0 + w][5];
        }
        const float denom = fmaxf(sqrtf(t0) * sqrtf(t1), 1e-24f);
        vals[tid] = t4 + t5 - 2.f * t3 * (t2 / denom);
    }
    __syncthreads();

    if (tid == 0) {
        const float blockVal = vals[0] + vals[1] + vals[2] + vals[3];
        __hip_atomic_store(&partials[blockIdx.x], blockVal,
                           __ATOMIC_RELAXED, __HIP_MEMORY_SCOPE_AGENT);
        __threadfence();
        const unsigned old = atomicInc(counter, NBLOCKS - 1u);  // cycles 0..7
        amLast = (old == NBLOCKS - 2u);                          // unique 8th arriver
    }
    __syncthreads();

    if (amLast && tid < 64) {
        __threadfence();
        float v = (tid < NBLOCKS)
            ? __hip_atomic_load(&partials[tid], __ATOMIC_RELAXED, __HIP_MEMORY_SCOPE_AGENT)
            : 0.f;
        #pragma unroll
        for (int off = 32; off >= 1; off >>= 1) v += __shfl_down(v, off);
        if (tid == 0) out[0] = v * (1.f / (float)(B * C));
    }
}

extern "C" void kernel_launch(void* const* d_in, const int* in_sizes, int n_in,
                              void* d_out, int out_size, void* d_ws, size_t ws_size,
                              hipStream_t stream) {
    const float* x = (const float*)d_in[0];
    const float* y = (const float*)d_in[1];
    float* partials = (float*)d_ws;                      // 8 floats (one line)
    unsigned* counter = (unsigned*)((char*)d_ws + 256);  // own cache line
    csl_fused8<<<NBLOCKS, THREADS, 0, stream>>>(x, y, partials, counter, (float*)d_out);
}

// Round 5
// 9.726 us; speedup vs baseline: 1.4606x; 1.0455x over previous
//
#include <hip/hip_runtime.h>

// ChannelSimLoss1D, single-dispatch, 32-block x 512-thread version.
// Closed form per sample: ||rowNormGram(x)-rowNormGram(y)||_F^2
//   = nnz(x) + nnz(y) - 2 * (sum_i sign(x_i)sign(y_i)) * cos(x,y)
// out = mean_b / C.  B=32, C=2048, fp32.
// One block per sample (R4 showed load parallelism across 32 CUs beats fewer
// arrivals); 512 threads -> exactly one float4 per array per thread.
// Finish: atomicInc(counter,31) cycles mod 32 -> exactly one block sees
// old==30 per call for ANY initial counter value (0xAA poison or steady-state
// 31), deterministic under graph replay with no re-poisoning.

constexpr int B = 32;
constexpr int C = 2048;
constexpr int THREADS = 512;            // 8 waves; C/4 = 512 float4 per array

__global__ __launch_bounds__(THREADS) void csl_fused32(const float* __restrict__ x,
                                                       const float* __restrict__ y,
                                                       float* __restrict__ partials,
                                                       unsigned* __restrict__ counter,
                                                       float* __restrict__ out) {
    const int tid  = threadIdx.x;
    const int wave = tid >> 6;          // 0..7
    const int lane = tid & 63;
    const int b    = blockIdx.x;        // sample

    // one float4 per array per thread, fully coalesced
    const float4 a  = reinterpret_cast<const float4*>(x + (size_t)b * C)[tid];
    const float4 c4 = reinterpret_cast<const float4*>(y + (size_t)b * C)[tid];

    float sx2 = 0.f, sy2 = 0.f, sxy = 0.f, sp = 0.f, cnt = 0.f;
    {
        const float av[4] = {a.x, a.y, a.z, a.w};
        const float bv[4] = {c4.x, c4.y, c4.z, c4.w};
        #pragma unroll
        for (int k = 0; k < 4; ++k) {
            const float u = av[k], v = bv[k];
            sx2 = fmaf(u, u, sx2);
            sy2 = fmaf(v, v, sy2);
            sxy = fmaf(u, v, sxy);
            const float su = (u > 0.f) ? 1.f : ((u < 0.f) ? -1.f : 0.f);
            const float sv = (v > 0.f) ? 1.f : ((v < 0.f) ? -1.f : 0.f);
            sp  = fmaf(su, sv, sp);
            // nnz(x)+nnz(y) combined (only the sum is needed); sign(0)=0
            // covers the reference's EPS branch exactly.
            cnt += ((u != 0.f) ? 1.f : 0.f) + ((v != 0.f) ? 1.f : 0.f);
        }
    }

    // 5-chain wave64 shuffle reduce
    #pragma unroll
    for (int off = 32; off >= 1; off >>= 1) {
        sx2 += __shfl_down(sx2, off);
        sy2 += __shfl_down(sy2, off);
        sxy += __shfl_down(sxy, off);
        sp  += __shfl_down(sp,  off);
        cnt += __shfl_down(cnt, off);
    }

    __shared__ float red[THREADS / 64][5];
    __shared__ bool  amLast;
    if (lane == 0) {
        red[wave][0] = sx2; red[wave][1] = sy2; red[wave][2] = sxy;
        red[wave][3] = sp;  red[wave][4] = cnt;
    }
    __syncthreads();

    if (tid == 0) {
        float t0 = 0.f, t1 = 0.f, t2 = 0.f, t3 = 0.f, t4 = 0.f;
        #pragma unroll
        for (int w = 0; w < THREADS / 64; ++w) {
            t0 += red[w][0]; t1 += red[w][1]; t2 += red[w][2];
            t3 += red[w][3]; t4 += red[w][4];
        }
        const float denom = fmaxf(sqrtf(t0) * sqrtf(t1), 1e-24f);
        const float val = t4 - 2.f * t3 * (t2 / denom);

        __hip_atomic_store(&partials[b], val, __ATOMIC_RELAXED, __HIP_MEMORY_SCOPE_AGENT);
        __threadfence();
        const unsigned old = atomicInc(counter, B - 1u);  // cycles 0..31
        amLast = (old == B - 2u);                         // unique 32nd arriver
    }
    __syncthreads();

    if (amLast && tid < 64) {
        __threadfence();
        float v = (tid < B)
            ? __hip_atomic_load(&partials[tid], __ATOMIC_RELAXED, __HIP_MEMORY_SCOPE_AGENT)
            : 0.f;
        #pragma unroll
        for (int off = 32; off >= 1; off >>= 1) v += __shfl_down(v, off);
        if (tid == 0) out[0] = v * (1.f / (float)(B * C));
    }
}

extern "C" void kernel_launch(void* const* d_in, const int* in_sizes, int n_in,
                              void* d_out, int out_size, void* d_ws, size_t ws_size,
                              hipStream_t stream) {
    const float* x = (const float*)d_in[0];
    const float* y = (const float*)d_in[1];
    float* partials = (float*)d_ws;                      // 32 floats
    unsigned* counter = (unsigned*)((char*)d_ws + 256);  // own cache line
    csl_fused32<<<B, THREADS, 0, stream>>>(x, y, partials, counter, (float*)d_out);
}